// Round 9
// baseline (541.906 us; speedup 1.0000x reference)
//
#include <hip/hip_runtime.h>
#include <stdint.h>

typedef __attribute__((ext_vector_type(8))) short bf16x8;
typedef __attribute__((ext_vector_type(4))) short bf16x4;
typedef __attribute__((ext_vector_type(4))) float f32x4;
typedef __attribute__((ext_vector_type(2))) unsigned u32x2;

__device__ __forceinline__ unsigned short f2bf(float f) {
  union { float f; unsigned u; } v; v.f = f;
  unsigned u = v.u;
  u += 0x7fffu + ((u >> 16) & 1u);
  return (unsigned short)(u >> 16);
}
__device__ __forceinline__ float bfpk_lo(unsigned pk) {
  union { unsigned u; float f; } v; v.u = pk << 16; return v.f;
}
__device__ __forceinline__ float bfpk_hi(unsigned pk) {
  union { unsigned u; float f; } v; v.u = pk & 0xffff0000u; return v.f;
}
__device__ __forceinline__ float stf(float x, float lam) {
  return x - fminf(fmaxf(x, -lam), lam);  // soft-threshold
}

// Fragment swizzle (A- and B-operand layouts are mirror images; same formula):
// element [k][n] lives at (((k>>5)*16 + (n>>4))*64 + (((k>>3)&3)*16 + (n&15)))*8 + (k&7)
__device__ __forceinline__ int swz_idx(int k, int n) {
  return ((((k >> 5) * 16 + (n >> 4)) * 64) + (((k >> 3) & 3) * 16 + (n & 15))) * 8 + (k & 7);
}

// stage[pos][feat], row stride 268 elems = 134 words. b64 gamma-writes: bank=(6m+2q+c)%32,
// 4 words/bank exact-uniform (zero excess). b128 B-reads: (6m+4q+c)%32, 8/bank uniform.
#define ST_STRIDE 268

// ---- module-scope scratch; fully rewritten every call ----
__device__ __attribute__((aligned(16))) unsigned short g_Acswz[65536];
__device__ __attribute__((aligned(16))) unsigned short g_Gswz[65536];
__device__ __attribute__((aligned(16))) unsigned short g_W3swz[65536];

// ---------------- fused prep: zero out + build all three swizzled matrices ----------------
__global__ void prep_all(const float* __restrict__ A, const float* __restrict__ Dw,
                         const float* __restrict__ Ww, float* __restrict__ out) {
  __shared__ float red[256];
  const int b = blockIdx.x;
  const int tid = threadIdx.x;
  out[b * 256 + tid] = 0.f;  // 768*256 == out_size exactly

  if (b < 256) {
    float s = 0.f;
    for (int c = tid; c < 243; c += 256) s += A[b * 243 + c];
    red[tid] = s;
    __syncthreads();
    for (int off = 128; off; off >>= 1) {
      if (tid < off) red[tid] += red[tid + off];
      __syncthreads();
    }
    float rm = red[0] * (1.f / 243.f);
    int k = tid;
    float v = 0.f;
    if (k < 243) {
      int rw = k / 9, j = k - rw * 9;
      int i = rw / 3, c = rw - i * 3;
      int corig = c * 81 + i * 9 + j;
      v = A[b * 243 + corig] - rm;
    }
    g_Acswz[swz_idx(k, b)] = f2bf(v);
  } else if (b < 512) {
    int f = b - 256, fp = tid;
    float s = 0.f;
    for (int c = 0; c < 243; ++c) s += A[f * 243 + c] * Dw[c * 256 + fp];
    g_Gswz[swz_idx(fp, f)] = f2bf(((f == fp) ? 1.f : 0.f) - s);
  } else {
    int cc = b - 512, f = tid;
    float v = 0.f;
    if (cc < 243) {
      int rw = cc / 9, j = cc - rw * 9;
      int i = rw / 3, c = rw - i * 3;
      int corig = c * 81 + i * 9 + j;
      v = Ww[corig * 256 + f];
    }
    g_W3swz[swz_idx(f, cc)] = f2bf(v);
  }
}

// ---- transposed GEMM, small wave tile: rows = 2 feature-tiles (2*wid, 2*wid+1),
// cols = 64 positions. Weights streamed from L2; positions/gamma from LDS stage.
// CMODE 0: C-init = 0; CMODE 1: C-init = unpacked bf16 lin.
template <int CMODE>
__device__ __forceinline__ void gemm_wave(const unsigned short* __restrict__ Asrc,
                                          const unsigned short* stg, int wid, int lane,
                                          int m, int q, f32x4 (&acc2)[2][4],
                                          const unsigned (&linpk)[2][4][2]) {
#pragma unroll
  for (int s = 0; s < 8; ++s) {
    bf16x8 acur[2];
#pragma unroll
    for (int tt = 0; tt < 2; ++tt)
      acur[tt] = *(const bf16x8*)(Asrc + (((s * 16 + 2 * wid + tt) * 64 + lane) << 3));
#pragma unroll
    for (int un = 0; un < 4; ++un) {
      const unsigned short* bp = stg + (un * 16 + m) * ST_STRIDE + s * 32 + q * 8;
      bf16x8 bfr = *(const bf16x8*)(bp);  // rows are 4B-aligned; loads are 8B-aligned pairs
#pragma unroll
      for (int tt = 0; tt < 2; ++tt) {
        f32x4 cin;
        if (s == 0) {
          if (CMODE == 1) {
            const unsigned* lp = linpk[tt][un];
            cin[0] = bfpk_lo(lp[0]);
            cin[1] = bfpk_hi(lp[0]);
            cin[2] = bfpk_lo(lp[1]);
            cin[3] = bfpk_hi(lp[1]);
          } else {
            cin = (f32x4){0.f, 0.f, 0.f, 0.f};
          }
        } else {
          cin = acc2[tt][un];
        }
        acc2[tt][un] = __builtin_amdgcn_mfma_f32_16x16x32_bf16(acur[tt], bfr, cin, 0, 0, 0);
      }
    }
  }
}

// ---------------- main fused kernel (transposed: M=features, N=positions) ----------------
// 900 blocks x 512 threads (8 waves; wave wid owns features [32*wid, 32*wid+32)).
// __launch_bounds__(512,4): 4 waves/SIMD -> 2 blocks/CU -> 16 waves/CU, 128-reg cap.
// Per-wave live state ~100 regs (acc 32 + linpk 16 + frags/temps) -> no spill expected.
__global__ __launch_bounds__(512, 4) void lista_fused(
    const float* __restrict__ I, const float* __restrict__ lmb, float* __restrict__ out) {
  __shared__ __attribute__((aligned(16))) unsigned short stage[64 * ST_STRIDE];  // 33.5 KB
  __shared__ float img[3][16][16];
  __shared__ float meanv[64];
  __shared__ float outacc[768];

  const int tid = threadIdx.x;
  const int lane = tid & 63;
  const int wid = tid >> 6;  // 0..7
  const int m = lane & 15;
  const int q = lane >> 4;

  const int blk = blockIdx.x;
  const int b = blk / 225;
  const int t2 = blk - b * 225;
  const int ty = t2 / 15;
  const int tx = t2 - ty * 15;
  const int py0 = ty * 8, px0 = tx * 8;

  const float* Ib = I + b * (3 * 128 * 128);
  for (int r = tid; r < 768; r += 512) {
    int c = r >> 8;
    int yx = r & 255;
    int y = yx >> 4, x = yx & 15;
    img[c][y][x] = Ib[c * 16384 + (py0 + y) * 128 + (px0 + x)];
    outacc[r] = 0.f;
  }
  if (tid < 64) meanv[tid] = 0.f;
  __syncthreads();

  // ---- build patch stage[pos][k] (k-order k=(i*3+c)*9+j) + per-position means ----
  {
    const int pos = tid & 63;
    const int part = tid >> 6;  // 0..7, handles k = part + 8*kk
    const int y = pos >> 3, x = pos & 7;
    int j = part, c = 0, i = 0;  // decode of k=part (<8 -> j=part)
    float s = 0.f;
    unsigned short* srow = &stage[pos * ST_STRIDE];
    for (int kk = 0; kk < 32; ++kk) {
      int k = part + 8 * kk;
      float v = 0.f;
      if (k < 243) { v = img[c][y + i][x + j]; s += v; }
      srow[k] = f2bf(v);
      j += 8;
      if (j >= 9) { j -= 9; if (++c == 3) { c = 0; ++i; } }
    }
    atomicAdd(&meanv[pos], s * (1.f / 243.f));
  }
  __syncthreads();

  unsigned linpk[2][4][2];  // [feat-tile tt][pos-tile un][2] packed bf16 lin

  // ---- GEMM1: lin[f][pos] = Ac @ patches^T; gamma0 = ST(lin) in-place ----
  {
    f32x4 acc2[2][4];
    gemm_wave<0>(g_Acswz, stage, wid, lane, m, q, acc2, linpk);
    __syncthreads();  // all patch reads done
#pragma unroll
    for (int tt = 0; tt < 2; ++tt) {
      const f32x4 lam4 = *(const f32x4*)(lmb + 32 * wid + tt * 16 + q * 4);
#pragma unroll
      for (int un = 0; un < 4; ++un) {
        linpk[tt][un][0] =
            (unsigned)f2bf(acc2[tt][un][0]) | ((unsigned)f2bf(acc2[tt][un][1]) << 16);
        linpk[tt][un][1] =
            (unsigned)f2bf(acc2[tt][un][2]) | ((unsigned)f2bf(acc2[tt][un][3]) << 16);
        float g0 = stf(acc2[tt][un][0], lam4[0]), g1 = stf(acc2[tt][un][1], lam4[1]);
        float g2 = stf(acc2[tt][un][2], lam4[2]), g3 = stf(acc2[tt][un][3], lam4[3]);
        u32x2 pk;
        pk[0] = (unsigned)f2bf(g0) | ((unsigned)f2bf(g1) << 16);
        pk[1] = (unsigned)f2bf(g2) | ((unsigned)f2bf(g3) << 16);
        *(u32x2*)(&stage[(un * 16 + m) * ST_STRIDE + 32 * wid + tt * 16 + q * 4]) = pk;
      }
    }
    __syncthreads();
  }

  // ---- 11 iterations: gamma' = ST(G2^T @ gamma + lin), in-place, 2 barriers ----
  for (int kk = 0; kk < 11; ++kk) {
    f32x4 acc2[2][4];
    gemm_wave<1>(g_Gswz, stage, wid, lane, m, q, acc2, linpk);
    __syncthreads();  // all gamma_k reads done
#pragma unroll
    for (int tt = 0; tt < 2; ++tt) {
      const f32x4 lam4 = *(const f32x4*)(lmb + (kk + 1) * 256 + 32 * wid + tt * 16 + q * 4);
#pragma unroll
      for (int un = 0; un < 4; ++un) {
        float g0 = stf(acc2[tt][un][0], lam4[0]), g1 = stf(acc2[tt][un][1], lam4[1]);
        float g2 = stf(acc2[tt][un][2], lam4[2]), g3 = stf(acc2[tt][un][3], lam4[3]);
        u32x2 pk;
        pk[0] = (unsigned)f2bf(g0) | ((unsigned)f2bf(g1) << 16);
        pk[1] = (unsigned)f2bf(g2) | ((unsigned)f2bf(g3) << 16);
        *(u32x2*)(&stage[(un * 16 + m) * ST_STRIDE + 32 * wid + tt * 16 + q * 4]) = pk;
      }
    }
    __syncthreads();  // gamma_{k+1} visible
  }

  // ---- GEMM3: out_cols[cc][pos] = W3 @ gamma_11 (+ mean) -> outacc atomics ----
  {
    f32x4 acc2[2][4];
    gemm_wave<0>(g_W3swz, stage, wid, lane, m, q, acc2, linpk);
#pragma unroll
    for (int tt = 0; tt < 2; ++tt)
#pragma unroll
      for (int r = 0; r < 4; ++r) {
        int cc = 32 * wid + tt * 16 + q * 4 + r;
        if (cc < 243) {
          int rw = cc / 9, jj = cc - rw * 9;
          int i = rw / 3, c = rw - i * 3;
#pragma unroll
          for (int un = 0; un < 4; ++un) {
            int pos = un * 16 + m;
            int y = (pos >> 3) + i, x = (pos & 7) + jj;
            atomicAdd(&outacc[c * 256 + y * 16 + x], acc2[tt][un][r] + meanv[pos]);
          }
        }
      }
  }
  __syncthreads();

  float* Ob = out + b * (3 * 128 * 128);
  for (int r = tid; r < 768; r += 512) {
    int c = r >> 8;
    int yx = r & 255;
    int y = yx >> 4, x = yx & 15;
    atomicAdd(&Ob[c * 16384 + (py0 + y) * 128 + (px0 + x)], outacc[r]);
  }
}

// divide by overlap counts
__global__ void div_counts(float* __restrict__ out, int n) {
  int idx = blockIdx.x * 256 + threadIdx.x;
  if (idx >= n) return;
  int x = idx & 127, y = (idx >> 7) & 127;
  int loy = y - 8; if (loy < 0) loy = 0;
  int hiy = y; if (hiy > 119) hiy = 119;
  int lox = x - 8; if (lox < 0) lox = 0;
  int hix = x; if (hix > 119) hix = 119;
  float cnt = (float)((hiy - loy + 1) * (hix - lox + 1));
  out[idx] = out[idx] / cnt;
}

extern "C" void kernel_launch(void* const* d_in, const int* in_sizes, int n_in,
                              void* d_out, int out_size, void* d_ws, size_t ws_size,
                              hipStream_t stream) {
  const float* I = (const float*)d_in[0];
  const float* A = (const float*)d_in[1];
  const float* Dw = (const float*)d_in[2];
  const float* Ww = (const float*)d_in[3];
  const float* lmb = (const float*)d_in[4];
  float* out = (float*)d_out;
  (void)d_ws; (void)ws_size;

  prep_all<<<768, 256, 0, stream>>>(A, Dw, Ww, out);
  lista_fused<<<900, 512, 0, stream>>>(I, lmb, out);
  div_counts<<<768, 256, 0, stream>>>(out, out_size);
}

// Round 10
// 302.583 us; speedup vs baseline: 1.7909x; 1.7909x over previous
//
#include <hip/hip_runtime.h>
#include <stdint.h>

typedef __attribute__((ext_vector_type(8))) short bf16x8;
typedef __attribute__((ext_vector_type(4))) float f32x4;
typedef __attribute__((ext_vector_type(2))) unsigned u32x2;

__device__ __forceinline__ unsigned short f2bf(float f) {
  union { float f; unsigned u; } v; v.f = f;
  unsigned u = v.u;
  u += 0x7fffu + ((u >> 16) & 1u);
  return (unsigned short)(u >> 16);
}
__device__ __forceinline__ float bfpk_lo(unsigned pk) {
  union { unsigned u; float f; } v; v.u = pk << 16; return v.f;
}
__device__ __forceinline__ float bfpk_hi(unsigned pk) {
  union { unsigned u; float f; } v; v.u = pk & 0xffff0000u; return v.f;
}
__device__ __forceinline__ float stf(float x, float lam) {
  return x - fminf(fmaxf(x, -lam), lam);  // soft-threshold
}

// Fragment swizzle (A- and B-operand layouts are mirror images; same formula):
// element [k][n] lives at (((k>>5)*16 + (n>>4))*64 + (((k>>3)&3)*16 + (n&15)))*8 + (k&7)
__device__ __forceinline__ int swz_idx(int k, int n) {
  return ((((k >> 5) * 16 + (n >> 4)) * 64) + (((k >> 3) & 3) * 16 + (n & 15))) * 8 + (k & 7);
}

// stage[pos][feat] stride 264 shorts (=132 words): b128 B-reads bank=(4m+16s+4q)%32 ->
// 8 words/bank exact-uniform; b64 gamma-writes (4m+8mt+2q)%32 -> <=2-way (free).
#define ST_STRIDE 264

// ---- module-scope scratch; fully rewritten every call ----
__device__ __attribute__((aligned(16))) unsigned short g_Acswz[65536];
__device__ __attribute__((aligned(16))) unsigned short g_Gswz[65536];
__device__ __attribute__((aligned(16))) unsigned short g_W3swz[65536];

// ---------------- fused prep: zero out + build all three swizzled matrices ----------------
__global__ void prep_all(const float* __restrict__ A, const float* __restrict__ Dw,
                         const float* __restrict__ Ww, float* __restrict__ out) {
  __shared__ float red[256];
  const int b = blockIdx.x;
  const int tid = threadIdx.x;
  out[b * 256 + tid] = 0.f;  // 768*256 == out_size exactly

  if (b < 256) {
    float s = 0.f;
    for (int c = tid; c < 243; c += 256) s += A[b * 243 + c];
    red[tid] = s;
    __syncthreads();
    for (int off = 128; off; off >>= 1) {
      if (tid < off) red[tid] += red[tid + off];
      __syncthreads();
    }
    float rm = red[0] * (1.f / 243.f);
    int k = tid;
    float v = 0.f;
    if (k < 243) {
      int rw = k / 9, j = k - rw * 9;
      int i = rw / 3, c = rw - i * 3;
      int corig = c * 81 + i * 9 + j;
      v = A[b * 243 + corig] - rm;
    }
    g_Acswz[swz_idx(k, b)] = f2bf(v);
  } else if (b < 512) {
    int f = b - 256, fp = tid;
    float s = 0.f;
    for (int c = 0; c < 243; ++c) s += A[f * 243 + c] * Dw[c * 256 + fp];
    g_Gswz[swz_idx(fp, f)] = f2bf(((f == fp) ? 1.f : 0.f) - s);
  } else {
    int cc = b - 512, f = tid;
    float v = 0.f;
    if (cc < 243) {
      int rw = cc / 9, j = cc - rw * 9;
      int i = rw / 3, c = rw - i * 3;
      int corig = c * 81 + i * 9 + j;
      v = Ww[corig * 256 + f];
    }
    g_W3swz[swz_idx(f, cc)] = f2bf(v);
  }
}

// ---- C-init helper ----
template <int CMODE>
__device__ __forceinline__ f32x4 cinit(const unsigned* lp) {
  if (CMODE == 1) {
    f32x4 c;
    c[0] = bfpk_lo(lp[0]);
    c[1] = bfpk_hi(lp[0]);
    c[2] = bfpk_lo(lp[1]);
    c[3] = bfpk_hi(lp[1]);
    return c;
  }
  return (f32x4){0.f, 0.f, 0.f, 0.f};
}

// ---- GEMM with A streamed from a global swizzled array (GEMM1 / GEMM3) ----
template <int CMODE>
__device__ __forceinline__ void gemm_glb(const unsigned short* __restrict__ Asrc,
                                         const unsigned short* stg, int w, int lane,
                                         int m, int q, f32x4 (&acc)[2][4],
                                         const unsigned (&linpk)[2][4][2]) {
#pragma unroll
  for (int s = 0; s < 8; ++s) {
    bf16x8 a0 = *(const bf16x8*)(Asrc + (((s * 16 + 2 * w) * 64 + lane) << 3));
    bf16x8 a1 = *(const bf16x8*)(Asrc + (((s * 16 + 2 * w + 1) * 64 + lane) << 3));
#pragma unroll
    for (int un = 0; un < 4; ++un) {
      bf16x8 bfr = *(const bf16x8*)(stg + (un * 16 + m) * ST_STRIDE + s * 32 + q * 8);
      f32x4 c0 = (s == 0) ? cinit<CMODE>(linpk[0][un]) : acc[0][un];
      f32x4 c1 = (s == 0) ? cinit<CMODE>(linpk[1][un]) : acc[1][un];
      acc[0][un] = __builtin_amdgcn_mfma_f32_16x16x32_bf16(a0, bfr, c0, 0, 0, 0);
      acc[1][un] = __builtin_amdgcn_mfma_f32_16x16x32_bf16(a1, bfr, c1, 0, 0, 0);
    }
  }
}

// ---- iteration GEMM: A (G2) from LDS; wave 7's second tile (ft=15) streams from L2 ----
template <bool TT1_GLOBAL>
__device__ __forceinline__ void gemm_iter(const unsigned short* g2l,
                                          const unsigned short* stg, int w, int lane,
                                          int m, int q, f32x4 (&acc)[2][4],
                                          const unsigned (&linpk)[2][4][2]) {
#pragma unroll
  for (int s = 0; s < 8; ++s) {
    bf16x8 a0 = *(const bf16x8*)(g2l + (((s * 15 + 2 * w) * 64 + lane) << 3));
    bf16x8 a1;
    if (TT1_GLOBAL)
      a1 = *(const bf16x8*)(g_Gswz + (((s * 16 + 15) * 64 + lane) << 3));
    else
      a1 = *(const bf16x8*)(g2l + (((s * 15 + 2 * w + 1) * 64 + lane) << 3));
#pragma unroll
    for (int un = 0; un < 4; ++un) {
      bf16x8 bfr = *(const bf16x8*)(stg + (un * 16 + m) * ST_STRIDE + s * 32 + q * 8);
      f32x4 c0 = (s == 0) ? cinit<1>(linpk[0][un]) : acc[0][un];
      f32x4 c1 = (s == 0) ? cinit<1>(linpk[1][un]) : acc[1][un];
      acc[0][un] = __builtin_amdgcn_mfma_f32_16x16x32_bf16(a0, bfr, c0, 0, 0, 0);
      acc[1][un] = __builtin_amdgcn_mfma_f32_16x16x32_bf16(a1, bfr, c1, 0, 0, 0);
    }
  }
}

// ---------------- main fused kernel ----------------
// 900 blocks x 512 threads (8 waves; wave w owns feature-tiles {2w,2w+1}); 1 block/CU
// (LDS-bound). G2 rows 0..14 cached in LDS once -> iteration loop has zero L2 traffic
// (except wave7's ft=15 row). (512,2) -> 256-reg cap, the proven no-spill zone.
__global__ __launch_bounds__(512, 2) void lista_fused(
    const float* __restrict__ I, const float* __restrict__ lmb, float* __restrict__ out) {
  __shared__ __attribute__((aligned(16))) unsigned short stage[64 * ST_STRIDE];   // 33792 B
  __shared__ __attribute__((aligned(16))) unsigned short g2lds[8 * 15 * 64 * 8];  // 122880 B
  __shared__ float img[3][16][16];                                                // 3072 B
  __shared__ float meanv[64];                                                     // 256 B
  __shared__ float outacc[768];                                                   // 3072 B

  const int tid = threadIdx.x;
  const int lane = tid & 63;
  const int w = tid >> 6;  // 0..7
  const int m = lane & 15;
  const int q = lane >> 4;

  const int blk = blockIdx.x;
  const int b = blk / 225;
  const int t2 = blk - b * 225;
  const int ty = t2 / 15;
  const int tx = t2 - ty * 15;
  const int py0 = ty * 8, px0 = tx * 8;

  const float* Ib = I + b * (3 * 128 * 128);
  for (int r = tid; r < 768; r += 512) {
    int c = r >> 8;
    int yx = r & 255;
    int y = yx >> 4, x = yx & 15;
    img[c][y][x] = Ib[c * 16384 + (py0 + y) * 128 + (px0 + x)];
    outacc[r] = 0.f;
  }
  if (tid < 64) meanv[tid] = 0.f;
  __syncthreads();

  // ---- build patch stage[pos][k] (k-order k=(i*3+c)*9+j) + per-position means ----
  {
    const int pos = tid & 63;
    const int part = tid >> 6;  // 0..7 handles k = part + 8*kk
    const int y = pos >> 3, x = pos & 7;
    int j = part, c = 0, i = 0;
    float s = 0.f;
    unsigned short* srow = &stage[pos * ST_STRIDE];
    for (int kk = 0; kk < 32; ++kk) {
      int k = part + 8 * kk;
      float v = 0.f;
      if (k < 243) { v = img[c][y + i][x + j]; s += v; }
      srow[k] = f2bf(v);
      j += 8;
      if (j >= 9) { j -= 9; if (++c == 3) { c = 0; ++i; } }
    }
    atomicAdd(&meanv[pos], s * (1.f / 243.f));
  }

  // ---- copy G2 rows ft=0..14 into LDS (each wave copies its own slice) ----
  {
#pragma unroll
    for (int i = 0; i < 16; ++i) {
      int ft = 2 * w + (i >> 3);
      int s = i & 7;
      if (ft < 15) {
        bf16x8 v = *(const bf16x8*)(g_Gswz + (((s * 16 + ft) * 64 + lane) << 3));
        *(bf16x8*)(g2lds + (((s * 15 + ft) * 64 + lane) << 3)) = v;
      }
    }
  }
  __syncthreads();

  unsigned linpk[2][4][2];  // [tt][pos-tile un][2] packed bf16 lin
  f32x4 acc[2][4];

  // ---- GEMM1: lin[f][pos] = Ac @ patches^T; gamma0 = ST(lin) in-place ----
  gemm_glb<0>(g_Acswz, stage, w, lane, m, q, acc, linpk);
  __syncthreads();  // all patch reads done
#pragma unroll
  for (int tt = 0; tt < 2; ++tt) {
    const f32x4 lam4 = *(const f32x4*)(lmb + (2 * w + tt) * 16 + q * 4);
#pragma unroll
    for (int un = 0; un < 4; ++un) {
      linpk[tt][un][0] = (unsigned)f2bf(acc[tt][un][0]) | ((unsigned)f2bf(acc[tt][un][1]) << 16);
      linpk[tt][un][1] = (unsigned)f2bf(acc[tt][un][2]) | ((unsigned)f2bf(acc[tt][un][3]) << 16);
      float g0 = stf(acc[tt][un][0], lam4[0]), g1 = stf(acc[tt][un][1], lam4[1]);
      float g2 = stf(acc[tt][un][2], lam4[2]), g3 = stf(acc[tt][un][3], lam4[3]);
      u32x2 pk;
      pk[0] = (unsigned)f2bf(g0) | ((unsigned)f2bf(g1) << 16);
      pk[1] = (unsigned)f2bf(g2) | ((unsigned)f2bf(g3) << 16);
      *(u32x2*)(&stage[(un * 16 + m) * ST_STRIDE + (2 * w + tt) * 16 + q * 4]) = pk;
    }
  }
  __syncthreads();

  // ---- 11 iterations: gamma' = ST(G2^T @ gamma + lin), in-place, 2 barriers ----
  for (int kk = 0; kk < 11; ++kk) {
    if (w < 7)
      gemm_iter<false>(g2lds, stage, w, lane, m, q, acc, linpk);
    else
      gemm_iter<true>(g2lds, stage, w, lane, m, q, acc, linpk);
    __syncthreads();  // all gamma_k reads done
#pragma unroll
    for (int tt = 0; tt < 2; ++tt) {
      const f32x4 lam4 = *(const f32x4*)(lmb + (kk + 1) * 256 + (2 * w + tt) * 16 + q * 4);
#pragma unroll
      for (int un = 0; un < 4; ++un) {
        float g0 = stf(acc[tt][un][0], lam4[0]), g1 = stf(acc[tt][un][1], lam4[1]);
        float g2 = stf(acc[tt][un][2], lam4[2]), g3 = stf(acc[tt][un][3], lam4[3]);
        u32x2 pk;
        pk[0] = (unsigned)f2bf(g0) | ((unsigned)f2bf(g1) << 16);
        pk[1] = (unsigned)f2bf(g2) | ((unsigned)f2bf(g3) << 16);
        *(u32x2*)(&stage[(un * 16 + m) * ST_STRIDE + (2 * w + tt) * 16 + q * 4]) = pk;
      }
    }
    __syncthreads();  // gamma_{k+1} visible
  }

  // ---- GEMM3: out_cols[cc][pos] = W3 @ gamma_11 (+ mean) -> outacc atomics ----
  gemm_glb<0>(g_W3swz, stage, w, lane, m, q, acc, linpk);
#pragma unroll
  for (int tt = 0; tt < 2; ++tt)
#pragma unroll
    for (int r = 0; r < 4; ++r) {
      int cc = (2 * w + tt) * 16 + q * 4 + r;
      if (cc < 243) {
        int rw = cc / 9, jj = cc - rw * 9;
        int i = rw / 3, c = rw - i * 3;
#pragma unroll
        for (int un = 0; un < 4; ++un) {
          int pos = un * 16 + m;
          int y = (pos >> 3) + i, x = (pos & 7) + jj;
          atomicAdd(&outacc[c * 256 + y * 16 + x], acc[tt][un][r] + meanv[pos]);
        }
      }
    }
  __syncthreads();

  float* Ob = out + b * (3 * 128 * 128);
  for (int r = tid; r < 768; r += 512) {
    int c = r >> 8;
    int yx = r & 255;
    int y = yx >> 4, x = yx & 15;
    atomicAdd(&Ob[c * 16384 + (py0 + y) * 128 + (px0 + x)], outacc[r]);
  }
}

// divide by overlap counts
__global__ void div_counts(float* __restrict__ out, int n) {
  int idx = blockIdx.x * 256 + threadIdx.x;
  if (idx >= n) return;
  int x = idx & 127, y = (idx >> 7) & 127;
  int loy = y - 8; if (loy < 0) loy = 0;
  int hiy = y; if (hiy > 119) hiy = 119;
  int lox = x - 8; if (lox < 0) lox = 0;
  int hix = x; if (hix > 119) hix = 119;
  float cnt = (float)((hiy - loy + 1) * (hix - lox + 1));
  out[idx] = out[idx] / cnt;
}

extern "C" void kernel_launch(void* const* d_in, const int* in_sizes, int n_in,
                              void* d_out, int out_size, void* d_ws, size_t ws_size,
                              hipStream_t stream) {
  const float* I = (const float*)d_in[0];
  const float* A = (const float*)d_in[1];
  const float* Dw = (const float*)d_in[2];
  const float* Ww = (const float*)d_in[3];
  const float* lmb = (const float*)d_in[4];
  float* out = (float*)d_out;
  (void)d_ws; (void)ws_size;

  prep_all<<<768, 256, 0, stream>>>(A, Dw, Ww, out);
  lista_fused<<<900, 512, 0, stream>>>(I, lmb, out);
  div_counts<<<768, 256, 0, stream>>>(out, out_size);
}

// Round 11
// 300.180 us; speedup vs baseline: 1.8053x; 1.0080x over previous
//
#include <hip/hip_runtime.h>
#include <stdint.h>

typedef __attribute__((ext_vector_type(8))) short bf16x8;
typedef __attribute__((ext_vector_type(4))) float f32x4;
typedef __attribute__((ext_vector_type(2))) unsigned u32x2;

__device__ __forceinline__ unsigned short f2bf(float f) {
  union { float f; unsigned u; } v; v.f = f;
  unsigned u = v.u;
  u += 0x7fffu + ((u >> 16) & 1u);
  return (unsigned short)(u >> 16);
}
__device__ __forceinline__ float bfpk_lo(unsigned pk) {
  union { unsigned u; float f; } v; v.u = pk << 16; return v.f;
}
__device__ __forceinline__ float bfpk_hi(unsigned pk) {
  union { unsigned u; float f; } v; v.u = pk & 0xffff0000u; return v.f;
}
__device__ __forceinline__ float stf(float x, float lam) {
  return x - fminf(fmaxf(x, -lam), lam);  // soft-threshold
}

// Fragment swizzle (A- and B-operand layouts are mirror images; same formula):
// element [k][n] lives at (((k>>5)*16 + (n>>4))*64 + (((k>>3)&3)*16 + (n&15)))*8 + (k&7)
__device__ __forceinline__ int swz_idx(int k, int n) {
  return ((((k >> 5) * 16 + (n >> 4)) * 64) + (((k >> 3) & 3) * 16 + (n & 15))) * 8 + (k & 7);
}

// stage[pos][feat] stride 264 shorts: b128 B-reads / b64 gamma-writes measured low-conflict
// in this configuration (r9: 0.9M total).
#define ST_STRIDE 264

// ---- module-scope scratch; fully rewritten every call ----
__device__ __attribute__((aligned(16))) unsigned short g_Acswz[65536];
__device__ __attribute__((aligned(16))) unsigned short g_Gswz[65536];
__device__ __attribute__((aligned(16))) unsigned short g_W3swz[65536];

// ---------------- fused prep: zero out + build all three swizzled matrices ----------------
__global__ void prep_all(const float* __restrict__ A, const float* __restrict__ Dw,
                         const float* __restrict__ Ww, float* __restrict__ out) {
  __shared__ float red[256];
  const int b = blockIdx.x;
  const int tid = threadIdx.x;
  out[b * 256 + tid] = 0.f;  // 768*256 == out_size exactly

  if (b < 256) {
    float s = 0.f;
    for (int c = tid; c < 243; c += 256) s += A[b * 243 + c];
    red[tid] = s;
    __syncthreads();
    for (int off = 128; off; off >>= 1) {
      if (tid < off) red[tid] += red[tid + off];
      __syncthreads();
    }
    float rm = red[0] * (1.f / 243.f);
    int k = tid;
    float v = 0.f;
    if (k < 243) {
      int rw = k / 9, j = k - rw * 9;
      int i = rw / 3, c = rw - i * 3;
      int corig = c * 81 + i * 9 + j;
      v = A[b * 243 + corig] - rm;
    }
    g_Acswz[swz_idx(k, b)] = f2bf(v);
  } else if (b < 512) {
    int f = b - 256, fp = tid;
    float s = 0.f;
    for (int c = 0; c < 243; ++c) s += A[f * 243 + c] * Dw[c * 256 + fp];
    g_Gswz[swz_idx(fp, f)] = f2bf(((f == fp) ? 1.f : 0.f) - s);
  } else {
    int cc = b - 512, f = tid;
    float v = 0.f;
    if (cc < 243) {
      int rw = cc / 9, j = cc - rw * 9;
      int i = rw / 3, c = rw - i * 3;
      int corig = c * 81 + i * 9 + j;
      v = Ww[corig * 256 + f];
    }
    g_W3swz[swz_idx(f, cc)] = f2bf(v);
  }
}

// ---- transposed GEMM, small wave tile: rows = 2 feature-tiles (2*wid, 2*wid+1),
// cols = 64 positions. Weights streamed from L2 with 1-ahead prefetch; B from LDS stage.
// CMODE 0: C-init = 0; CMODE 1: C-init = unpacked bf16 lin.
template <int CMODE>
__device__ __forceinline__ void gemm_wave(const unsigned short* __restrict__ Asrc,
                                          const unsigned short* stg, int wid, int lane,
                                          int m, int q, f32x4 (&acc2)[2][4],
                                          const unsigned (&linpk)[2][4][2]) {
  bf16x8 acur[2];
#pragma unroll
  for (int tt = 0; tt < 2; ++tt)
    acur[tt] = *(const bf16x8*)(Asrc + (((2 * wid + tt) * 64 + lane) << 3));
#pragma unroll
  for (int s = 0; s < 8; ++s) {
    bf16x8 anext[2];
    if (s < 7) {
#pragma unroll
      for (int tt = 0; tt < 2; ++tt)
        anext[tt] =
            *(const bf16x8*)(Asrc + ((((s + 1) * 16 + 2 * wid + tt) * 64 + lane) << 3));
    }
#pragma unroll
    for (int un = 0; un < 4; ++un) {
      bf16x8 bfr = *(const bf16x8*)(stg + (un * 16 + m) * ST_STRIDE + s * 32 + q * 8);
#pragma unroll
      for (int tt = 0; tt < 2; ++tt) {
        f32x4 cin;
        if (s == 0) {
          if (CMODE == 1) {
            const unsigned* lp = linpk[tt][un];
            cin[0] = bfpk_lo(lp[0]);
            cin[1] = bfpk_hi(lp[0]);
            cin[2] = bfpk_lo(lp[1]);
            cin[3] = bfpk_hi(lp[1]);
          } else {
            cin = (f32x4){0.f, 0.f, 0.f, 0.f};
          }
        } else {
          cin = acc2[tt][un];
        }
        acc2[tt][un] = __builtin_amdgcn_mfma_f32_16x16x32_bf16(acur[tt], bfr, cin, 0, 0, 0);
      }
    }
    if (s < 7) {
      acur[0] = anext[0];
      acur[1] = anext[1];
    }
  }
}

// ---------------- main fused kernel (transposed: M=features, N=positions) ----------------
// 900 blocks x 512 threads (8 waves; wave wid owns features [32*wid, 32*wid+32)).
// __launch_bounds__(512,2): relaxed 256-reg budget (proven no-spill); body ~90-120 regs,
// LDS 40 KB -> hardware co-schedules 2 blocks/CU = 16 waves/CU = 4 waves/SIMD.
// (512,4) would CAP arch-VGPRs at 64 and spill — r9's mistake.
__global__ __launch_bounds__(512, 2) void lista_fused(
    const float* __restrict__ I, const float* __restrict__ lmb, float* __restrict__ out) {
  __shared__ __attribute__((aligned(16))) unsigned short stage[64 * ST_STRIDE];  // 33792 B
  __shared__ float img[3][16][16];
  __shared__ float meanv[64];
  __shared__ float outacc[768];

  const int tid = threadIdx.x;
  const int lane = tid & 63;
  const int wid = tid >> 6;  // 0..7
  const int m = lane & 15;
  const int q = lane >> 4;

  const int blk = blockIdx.x;
  const int b = blk / 225;
  const int t2 = blk - b * 225;
  const int ty = t2 / 15;
  const int tx = t2 - ty * 15;
  const int py0 = ty * 8, px0 = tx * 8;

  const float* Ib = I + b * (3 * 128 * 128);
  for (int r = tid; r < 768; r += 512) {
    int c = r >> 8;
    int yx = r & 255;
    int y = yx >> 4, x = yx & 15;
    img[c][y][x] = Ib[c * 16384 + (py0 + y) * 128 + (px0 + x)];
    outacc[r] = 0.f;
  }
  if (tid < 64) meanv[tid] = 0.f;
  __syncthreads();

  // ---- build patch stage[pos][k] (k-order k=(i*3+c)*9+j) + per-position means ----
  {
    const int pos = tid & 63;
    const int part = tid >> 6;  // 0..7 handles k = part + 8*kk
    const int y = pos >> 3, x = pos & 7;
    int j = part, c = 0, i = 0;
    float s = 0.f;
    unsigned short* srow = &stage[pos * ST_STRIDE];
    for (int kk = 0; kk < 32; ++kk) {
      int k = part + 8 * kk;
      float v = 0.f;
      if (k < 243) { v = img[c][y + i][x + j]; s += v; }
      srow[k] = f2bf(v);
      j += 8;
      if (j >= 9) { j -= 9; if (++c == 3) { c = 0; ++i; } }
    }
    atomicAdd(&meanv[pos], s * (1.f / 243.f));
  }
  __syncthreads();

  unsigned linpk[2][4][2];  // [feat-tile tt][pos-tile un][2] packed bf16 lin

  // ---- GEMM1: lin[f][pos] = Ac @ patches^T; gamma0 = ST(lin) in-place ----
  {
    f32x4 acc2[2][4];
    gemm_wave<0>(g_Acswz, stage, wid, lane, m, q, acc2, linpk);
    __syncthreads();  // all patch reads done
#pragma unroll
    for (int tt = 0; tt < 2; ++tt) {
      const f32x4 lam4 = *(const f32x4*)(lmb + 32 * wid + tt * 16 + q * 4);
#pragma unroll
      for (int un = 0; un < 4; ++un) {
        linpk[tt][un][0] =
            (unsigned)f2bf(acc2[tt][un][0]) | ((unsigned)f2bf(acc2[tt][un][1]) << 16);
        linpk[tt][un][1] =
            (unsigned)f2bf(acc2[tt][un][2]) | ((unsigned)f2bf(acc2[tt][un][3]) << 16);
        float g0 = stf(acc2[tt][un][0], lam4[0]), g1 = stf(acc2[tt][un][1], lam4[1]);
        float g2 = stf(acc2[tt][un][2], lam4[2]), g3 = stf(acc2[tt][un][3], lam4[3]);
        u32x2 pk;
        pk[0] = (unsigned)f2bf(g0) | ((unsigned)f2bf(g1) << 16);
        pk[1] = (unsigned)f2bf(g2) | ((unsigned)f2bf(g3) << 16);
        *(u32x2*)(&stage[(un * 16 + m) * ST_STRIDE + 32 * wid + tt * 16 + q * 4]) = pk;
      }
    }
    __syncthreads();
  }

  // ---- 11 iterations: gamma' = ST(G2^T @ gamma + lin), in-place, 2 barriers ----
  for (int kk = 0; kk < 11; ++kk) {
    f32x4 acc2[2][4];
    gemm_wave<1>(g_Gswz, stage, wid, lane, m, q, acc2, linpk);
    __syncthreads();  // all gamma_k reads done
#pragma unroll
    for (int tt = 0; tt < 2; ++tt) {
      const f32x4 lam4 = *(const f32x4*)(lmb + (kk + 1) * 256 + 32 * wid + tt * 16 + q * 4);
#pragma unroll
      for (int un = 0; un < 4; ++un) {
        float g0 = stf(acc2[tt][un][0], lam4[0]), g1 = stf(acc2[tt][un][1], lam4[1]);
        float g2 = stf(acc2[tt][un][2], lam4[2]), g3 = stf(acc2[tt][un][3], lam4[3]);
        u32x2 pk;
        pk[0] = (unsigned)f2bf(g0) | ((unsigned)f2bf(g1) << 16);
        pk[1] = (unsigned)f2bf(g2) | ((unsigned)f2bf(g3) << 16);
        *(u32x2*)(&stage[(un * 16 + m) * ST_STRIDE + 32 * wid + tt * 16 + q * 4]) = pk;
      }
    }
    __syncthreads();  // gamma_{k+1} visible
  }

  // ---- GEMM3: out_cols[cc][pos] = W3 @ gamma_11 (+ mean) -> outacc atomics ----
  {
    f32x4 acc2[2][4];
    gemm_wave<0>(g_W3swz, stage, wid, lane, m, q, acc2, linpk);
#pragma unroll
    for (int tt = 0; tt < 2; ++tt)
#pragma unroll
      for (int r = 0; r < 4; ++r) {
        int cc = 32 * wid + tt * 16 + q * 4 + r;
        if (cc < 243) {
          int rw = cc / 9, jj = cc - rw * 9;
          int i = rw / 3, c = rw - i * 3;
#pragma unroll
          for (int un = 0; un < 4; ++un) {
            int pos = un * 16 + m;
            int y = (pos >> 3) + i, x = (pos & 7) + jj;
            atomicAdd(&outacc[c * 256 + y * 16 + x], acc2[tt][un][r] + meanv[pos]);
          }
        }
      }
  }
  __syncthreads();

  float* Ob = out + b * (3 * 128 * 128);
  for (int r = tid; r < 768; r += 512) {
    int c = r >> 8;
    int yx = r & 255;
    int y = yx >> 4, x = yx & 15;
    atomicAdd(&Ob[c * 16384 + (py0 + y) * 128 + (px0 + x)], outacc[r]);
  }
}

// divide by overlap counts
__global__ void div_counts(float* __restrict__ out, int n) {
  int idx = blockIdx.x * 256 + threadIdx.x;
  if (idx >= n) return;
  int x = idx & 127, y = (idx >> 7) & 127;
  int loy = y - 8; if (loy < 0) loy = 0;
  int hiy = y; if (hiy > 119) hiy = 119;
  int lox = x - 8; if (lox < 0) lox = 0;
  int hix = x; if (hix > 119) hix = 119;
  float cnt = (float)((hiy - loy + 1) * (hix - lox + 1));
  out[idx] = out[idx] / cnt;
}

extern "C" void kernel_launch(void* const* d_in, const int* in_sizes, int n_in,
                              void* d_out, int out_size, void* d_ws, size_t ws_size,
                              hipStream_t stream) {
  const float* I = (const float*)d_in[0];
  const float* A = (const float*)d_in[1];
  const float* Dw = (const float*)d_in[2];
  const float* Ww = (const float*)d_in[3];
  const float* lmb = (const float*)d_in[4];
  float* out = (float*)d_out;
  (void)d_ws; (void)ws_size;

  prep_all<<<768, 256, 0, stream>>>(A, Dw, Ww, out);
  lista_fused<<<900, 512, 0, stream>>>(I, lmb, out);
  div_counts<<<768, 256, 0, stream>>>(out, out_size);
}